// Round 5
// baseline (257.453 us; speedup 1.0000x reference)
//
#include <hip/hip_runtime.h>

// Cost volume: out[b,d,h,w] = (w>=d) ? (1/32) * sum_c L[b,c,h,w]*R[b,c,h,w-d] : 0
// B=4, C=32, H=256, W=512, D=64, fp32 (no fp32-input MFMA on CDNA4).
//
// v5 (wave-autonomous round): v1-v4 (dbuf / 2x-occupancy / gload_lds-dbuf /
// counted-vmcnt ring) ALL land 88-113 us with every pipe <35% busy. Per-CU
// pipe budget: VALU 15us, LDS 26-31us, read-port 20us, HBM-write 22us ->
// overlapped ~30us, serialized ~90us = measured. Diagnosis: block-wide
// s_barrier phase-locks all waves -> pipes take turns. v4's proof: its DMA
// writes collided with ds_reads (conflicts 1.05e7 -> 1.84e7) because the
// barrier kept everyone in lockstep.
//
// Fix: NO BARRIERS AT ALL. 1 wave per block (64 thr), 4096 blocks; each wave
// owns (b, h, w-half, d-half): acc[32][4]. Private 13.3KB LDS ring (4 slots:
// R row 576f + L slice 256f), staged via global_load_lds 3 channels ahead,
// per-wave counted s_waitcnt vmcnt(9). Waves self-pace -> pipes overlap
// statistically. R staged 4x, L 2x (dup ~800MB, L2/L3-served: ~11us/CU).
// Per channel per lane: 9 live ds_read_b128 (R window, 16B lane stride,
// conflict-free) + 1 L read + 128 FMA.

constexpr int Bn = 4, Cn = 32, Hn = 256, Wn = 512, Dn = 64;
constexpr int HW  = Hn * Wn;         // 131072
constexpr int PAD = 64;              // zero pad -> automatic w<d masking
constexpr int SLOTR = PAD + Wn;      // 576 floats: R row (full, 2 DMA instrs)
constexpr int SLOTL = 256;           // 256 floats: L w-half slice (1 DMA instr)
constexpr int SLOT  = SLOTR + SLOTL; // 832 floats = 3328 B
constexpr int NBUF  = 4;             // ring slots, 3 channels ahead

__global__ __launch_bounds__(64, 2)
void cost_volume_kernel(const float* __restrict__ left,
                        const float* __restrict__ right,
                        float* __restrict__ out)
{
    __shared__ __align__(16) float Buf[NBUF][SLOT];   // 13,312 B -> 8 blocks/CU

    const int lane = threadIdx.x;          // 0..63 (one wave per block)
    const int row  = blockIdx.x;           // (b,h); 1024 rows
    const int quad = blockIdx.y;           // 0..3; same row -> same XCD (1024%8==0)
    const int wh   = (quad & 1) << 8;      // w-half base: 0 or 256
    const int dh   = (quad >> 1) << 5;     // d-half base: 0 or 32
    const int b    = row >> 8;             // H = 256
    const int h    = row & (Hn - 1);

    const float* Lrow = left  + (b * Cn * Hn + h) * Wn;   // channel stride = HW
    const float* Rrow = right + (b * Cn * Hn + h) * Wn;

    // --- zero the R pads of all 4 slots: 4 x 64 floats = 64 float4, 1/lane.
    // Single wave -> no barrier; compiler orders LDS ops via lgkmcnt.
    {
        const int s = lane >> 4;
        const int o = (lane & 15) << 2;
        *reinterpret_cast<float4*>(&Buf[s][o]) = make_float4(0.f, 0.f, 0.f, 0.f);
    }

    const int l4 = lane << 2;

    // one channel = 3 DMA instrs: R row (2 x 1KB) + L slice (1 x 1KB).
    // LDS dest = wave-uniform base + lane*16 (pattern identical to v2-v4).
    auto stage = [&](int slot, int c) {
        const float* rsrc = Rrow + c * HW + l4;
        __builtin_amdgcn_global_load_lds(
            (const __attribute__((address_space(1))) void*)rsrc,
            (__attribute__((address_space(3))) void*)&Buf[slot][PAD + l4],
            16, 0, 0);
        __builtin_amdgcn_global_load_lds(
            (const __attribute__((address_space(1))) void*)(rsrc + 256),
            (__attribute__((address_space(3))) void*)&Buf[slot][PAD + 256 + l4],
            16, 0, 0);
        __builtin_amdgcn_global_load_lds(
            (const __attribute__((address_space(1))) void*)(Lrow + c * HW + wh + l4),
            (__attribute__((address_space(3))) void*)&Buf[slot][SLOTR + l4],
            16, 0, 0);
    };

    // prologue: 3 channels in flight (9 outstanding DMA ops for this wave)
    stage(0, 0);
    stage(1, 1);
    stage(2, 2);

    float acc[32][4];
    #pragma unroll
    for (int j = 0; j < 32; ++j)
        #pragma unroll
        for (int i = 0; i < 4; ++i)
            acc[j][i] = 0.f;

    // window base: r[k] = Sb[rbase + k]; slot float p<64 is 0, else R[p-64].
    // acc[j][i] needs R[wh+4l+i-dh-j] -> r[32+i-j], idx in [1,35] of r[0..39]
    // (r[0], r[36..39] dead -> 10th read eliminated; 9 live reads).
    const int rbase = PAD + wh + l4 - dh - 32;   // >= 0, multiple of 4

    auto compute = [&](int c) {
        const float* Sb = &Buf[c & (NBUF - 1)][0];
        const float4 Lv = *reinterpret_cast<const float4*>(&Sb[SLOTR + l4]);
        float r[40];
        #pragma unroll
        for (int q = 0; q < 10; ++q)
            *reinterpret_cast<float4*>(&r[q * 4]) =
                *reinterpret_cast<const float4*>(&Sb[rbase + q * 4]);
        #pragma unroll
        for (int j = 0; j < 32; ++j) {
            acc[j][0] = fmaf(Lv.x, r[32 - j], acc[j][0]);
            acc[j][1] = fmaf(Lv.y, r[33 - j], acc[j][1]);
            acc[j][2] = fmaf(Lv.z, r[34 - j], acc[j][2]);
            acc[j][3] = fmaf(Lv.w, r[35 - j], acc[j][3]);
        }
    };

    // main loop: stage 3 ahead, then counted wait. After stage: 12 DMA
    // outstanding (channels c..c+3); vmcnt(9) completes channel c's 3.
    // Ring WAR is safe: stage(c+3) overwrites slot (c-1)&3, whose ds_reads
    // were consumed by iter c-1's FMAs (program order + LDS aliasing).
    for (int c = 0; c < Cn - 3; ++c) {
        __builtin_amdgcn_sched_barrier(0);
        stage((c + 3) & (NBUF - 1), c + 3);
        asm volatile("s_waitcnt vmcnt(9)" ::: "memory");
        __builtin_amdgcn_sched_barrier(0);
        compute(c);
    }
    // tail: drain 9 -> 6 -> 3 -> 0
    asm volatile("s_waitcnt vmcnt(6)" ::: "memory");
    __builtin_amdgcn_sched_barrier(0);
    compute(Cn - 3);
    asm volatile("s_waitcnt vmcnt(3)" ::: "memory");
    __builtin_amdgcn_sched_barrier(0);
    compute(Cn - 2);
    asm volatile("s_waitcnt vmcnt(0)" ::: "memory");
    __builtin_amdgcn_sched_barrier(0);
    compute(Cn - 1);

    // --- epilogue: out[b][dh+j][h][wh + 4l .. +3], 1KB contiguous per store
    constexpr float inv = 1.0f / 32.0f;
    float* op = out + ((b * Dn + dh) * Hn + h) * Wn + wh + l4;
    #pragma unroll
    for (int j = 0; j < 32; ++j) {
        const float4 v = make_float4(acc[j][0] * inv, acc[j][1] * inv,
                                     acc[j][2] * inv, acc[j][3] * inv);
        *reinterpret_cast<float4*>(&op[j * HW]) = v;
    }
}

extern "C" void kernel_launch(void* const* d_in, const int* in_sizes, int n_in,
                              void* d_out, int out_size, void* d_ws, size_t ws_size,
                              hipStream_t stream) {
    const float* left  = (const float*)d_in[0];
    const float* right = (const float*)d_in[1];
    float* out = (float*)d_out;
    cost_volume_kernel<<<dim3(Bn * Hn, 4), dim3(64), 0, stream>>>(left, right, out);
}